// Round 1
// baseline (84530.334 us; speedup 1.0000x reference)
//
#include <hip/hip_runtime.h>

// EarthMoverDistance: exact Hungarian (Jonker-Volgenant, e-maxx formulation)
// B=8 batches, N=1024 points, 3-D Euclidean cost. One wave (64 lanes) per
// batch; each lane owns 16 columns in registers. Deferred potential updates:
// minv stored in "absolute" (path-distance) form so no per-iteration u/v/minv
// sweeps are needed -- verified algebraically identical to the reference.

#define N     1024
#define BATCH 8
#define NSLOT 16          // columns per lane: 64 lanes * 16 = 1024
#define INFV  1e9f

__global__ void emd_zero_kernel(float* out) { out[0] = 0.0f; }

__global__ __launch_bounds__(64, 1)
void emd_jv_kernel(const float* __restrict__ S1,
                   const float* __restrict__ S2,
                   float* __restrict__ out) {
    __shared__ float s1[N * 3];       // batch's S1 points, flat xyz
    __shared__ float u_lds[N + 1];    // row potentials (1-indexed)
    __shared__ int   p_lds[N + 1];    // p[j] = row matched to column j
    __shared__ float dentry[N + 1];   // D value when column became "used"

    const int lane = threadIdx.x;     // 0..63
    const int b = blockIdx.x;
    const float* s1g = S1 + (size_t)b * N * 3;
    const float* s2g = S2 + (size_t)b * N * 3;

    // ---- init LDS ----
    for (int t = lane; t < N * 3; t += 64) s1[t] = s1g[t];
    for (int t = lane; t <= N; t += 64) { u_lds[t] = 0.0f; p_lds[t] = 0; }

    // ---- per-lane column state (col j = 1 + k*64 + lane) ----
    float x2[NSLOT], y2[NSLOT], z2[NSLOT], v[NSLOT];
#pragma unroll
    for (int k = 0; k < NSLOT; ++k) {
        int pt = k * 64 + lane;             // S2 point index = j-1
        x2[k] = s2g[3 * pt + 0];
        y2[k] = s2g[3 * pt + 1];
        z2[k] = s2g[3 * pt + 2];
        v[k] = 0.0f;
    }
    __syncthreads();

    for (int i = 1; i <= N; ++i) {
        // ---------- row step: Dijkstra-like search ----------
        float minv[NSLOT];   // absolute path distances (minv + accumulated D)
        int   way[NSLOT];
#pragma unroll
        for (int k = 0; k < NSLOT; ++k) { minv[k] = INFV; way[k] = 0; }
        unsigned used = 0u;
        float Dprev = 0.0f;

        if (lane == 0) p_lds[0] = i;
        __syncthreads();

        int j0 = 0;
        int guard = 0;
        for (;;) {
            int i0 = __builtin_amdgcn_readfirstlane(p_lds[j0]);
            if (i0 == 0) break;            // unmatched column found -> augment
            if (++guard > N + 2) break;    // safety (should never trigger)

            // mark j0 used (j0 >= 1 after first iteration; col 0 has no slot)
            if (j0 > 0) {
                int c = j0 - 1;
                int k0 = c >> 6, l0 = c & 63;
                if (lane == 0) dentry[j0] = Dprev;
                bool me = (lane == l0);
                if (me) used |= (1u << k0);
                // settled column must never be selected again
#pragma unroll
                for (int k = 0; k < NSLOT; ++k)
                    minv[k] = (me && k == k0) ? INFV : minv[k];
            }

            // expand from row i0 (pre-row-step potentials; see derivation)
            float x1 = s1[3 * (i0 - 1) + 0];
            float y1 = s1[3 * (i0 - 1) + 1];
            float z1 = s1[3 * (i0 - 1) + 2];
            float base = Dprev - u_lds[i0];
#pragma unroll
            for (int k = 0; k < NSLOT; ++k) {
                float dx = x1 - x2[k], dy = y1 - y2[k], dz = z1 - z2[k];
                float d = sqrtf(dx * dx + dy * dy + dz * dz);
                float curabs = d + (base - v[k]);
                bool upd = (curabs < minv[k]) && !((used >> k) & 1u);
                minv[k] = upd ? curabs : minv[k];
                way[k]  = upd ? j0 : way[k];
            }

            // argmin over 1024 columns: 16-slot local, then 64-lane butterfly
            float bestv = minv[0];
            int   bestj = 1 + lane;
#pragma unroll
            for (int k = 1; k < NSLOT; ++k) {
                int j = 1 + k * 64 + lane;
                if (minv[k] < bestv) { bestv = minv[k]; bestj = j; }
            }
#pragma unroll
            for (int off = 32; off >= 1; off >>= 1) {
                float ov = __shfl_xor(bestv, off);
                int   oj = __shfl_xor(bestj, off);
                if (ov < bestv) { bestv = ov; bestj = oj; }
            }
            Dprev = bestv;
            j0 = __builtin_amdgcn_readfirstlane(bestj);
        }
        float DT = Dprev;
        __syncthreads();

        // ---------- deferred potential updates ----------
        // column 0 (always used, p[0]=i): u[i] += DT - 0
        if (lane == 0) u_lds[i] += DT;
#pragma unroll
        for (int k = 0; k < NSLOT; ++k) {
            if ((used >> k) & 1u) {
                int j = 1 + k * 64 + lane;
                float dd = DT - dentry[j];
                v[k] -= dd;
                int r = p_lds[j];       // distinct rows across used cols
                u_lds[r] += dd;         // race-free non-atomic RMW
            }
        }
        __syncthreads();

        // ---------- augment along alternating path ----------
        int aguard = 0;
        while (j0 != 0) {
            if (++aguard > N + 2) break;
            int c = j0 - 1;
            int k0 = c >> 6, l0 = c & 63;
            int wsel = way[0];
#pragma unroll
            for (int k = 1; k < NSLOT; ++k) wsel = (k == k0) ? way[k] : wsel;
            int j1 = __shfl(wsel, l0);
            int pj1 = p_lds[j1];        // read before write (j1 != j0)
            if (lane == 0) p_lds[j0] = pj1;
            __syncthreads();
            j0 = j1;
        }
        __syncthreads();
    }

    // ---------- total matched cost ----------
    float sum = 0.0f;
#pragma unroll
    for (int k = 0; k < NSLOT; ++k) {
        int j = 1 + k * 64 + lane;
        int r = p_lds[j];
        float x1 = s1[3 * (r - 1) + 0];
        float y1 = s1[3 * (r - 1) + 1];
        float z1 = s1[3 * (r - 1) + 2];
        float dx = x1 - x2[k], dy = y1 - y2[k], dz = z1 - z2[k];
        sum += sqrtf(dx * dx + dy * dy + dz * dz);
    }
#pragma unroll
    for (int off = 32; off >= 1; off >>= 1) sum += __shfl_xor(sum, off);
    if (lane == 0) atomicAdd(out, sum * (1.0f / ((float)N * (float)BATCH)));
}

extern "C" void kernel_launch(void* const* d_in, const int* in_sizes, int n_in,
                              void* d_out, int out_size, void* d_ws, size_t ws_size,
                              hipStream_t stream) {
    const float* S1 = (const float*)d_in[0];
    const float* S2 = (const float*)d_in[1];
    float* out = (float*)d_out;
    emd_zero_kernel<<<1, 1, 0, stream>>>(out);
    emd_jv_kernel<<<BATCH, 64, 0, stream>>>(S1, S2, out);
}

// Round 2
// 56973.090 us; speedup vs baseline: 1.4837x; 1.4837x over previous
//
#include <hip/hip_runtime.h>

// EarthMoverDistance: exact Hungarian (Jonker-Volgenant successive shortest
// path) with JV column-reduction + greedy initialization. B=8, N=1024, 3-D
// Euclidean cost. One wave per batch; lane owns 16 columns in registers.
// Deferred potential updates (minv kept in absolute path-distance form) --
// algebraically identical to the reference (round-1 absmax was 0.0).
// Argmin: per-lane 16-slot reduce -> DPP f32 min-reduce (6 VALU steps) ->
// readlane(63) -> ballot+readlane for the index. Exact.

#define N     1024
#define BATCH 8
#define NSLOT 16          // columns per lane: 64 lanes * 16 = 1024
#define INFV  1e9f

__global__ void emd_zero_kernel(float* out) { out[0] = 0.0f; }

template<int CTRL>
__device__ __forceinline__ float dppmin(float x) {
    int xi = __float_as_int(x);
    int yi = __builtin_amdgcn_update_dpp(xi, xi, CTRL, 0xF, 0xF, false);
    return fminf(x, __int_as_float(yi));
}

// full-wave (64 lane) f32 min; result valid in lane 63, broadcast via readlane
__device__ __forceinline__ float wave_min_f32(float x) {
    x = dppmin<0x111>(x);   // row_shr:1
    x = dppmin<0x112>(x);   // row_shr:2
    x = dppmin<0x114>(x);   // row_shr:4
    x = dppmin<0x118>(x);   // row_shr:8  -> lane15 of each row has row min
    x = dppmin<0x142>(x);   // row_bcast:15
    x = dppmin<0x143>(x);   // row_bcast:31 -> lane 63 has global min
    return __int_as_float(__builtin_amdgcn_readlane(__float_as_int(x), 63));
}

__global__ __launch_bounds__(64, 1)
void emd_jv_kernel(const float* __restrict__ S1,
                   const float* __restrict__ S2,
                   float* __restrict__ out) {
    __shared__ float4 s1u[N + 1];     // per row r: {x, y, z, u[r]}
    __shared__ int    p_lds[N + 1];   // p[j] = row matched to column j
    __shared__ float  dentry[N + 1];  // D value when column became "used"
    __shared__ int    rowm[N + 1];    // row -> matching col (0 = free)

    const int lane = threadIdx.x;     // 0..63
    const int b = blockIdx.x;
    const float* s1g = S1 + (size_t)b * N * 3;
    const float* s2g = S2 + (size_t)b * N * 3;

    // ---- init LDS ----
    for (int t = lane; t < N; t += 64)
        s1u[t + 1] = make_float4(s1g[3 * t], s1g[3 * t + 1], s1g[3 * t + 2], 0.0f);
    for (int t = lane; t <= N; t += 64) { p_lds[t] = 0; rowm[t] = 0; }

    // ---- per-lane column state (col j = 1 + k*64 + lane) ----
    float x2[NSLOT], y2[NSLOT], z2[NSLOT], v[NSLOT];
    int   imin[NSLOT];
#pragma unroll
    for (int k = 0; k < NSLOT; ++k) {
        int pt = k * 64 + lane;             // S2 point index = j-1
        x2[k] = s2g[3 * pt + 0];
        y2[k] = s2g[3 * pt + 1];
        z2[k] = s2g[3 * pt + 2];
        v[k] = INFV;                        // reused as best squared dist
        imin[k] = 1;
    }
    __syncthreads();

    // ---- JV column reduction: v[j] = min_i dist(i,j), imin = argmin ----
    for (int r = 1; r <= N; ++r) {
        float4 q = s1u[r];                  // broadcast ds_read_b128
#pragma unroll
        for (int k = 0; k < NSLOT; ++k) {
            float dx = q.x - x2[k], dy = q.y - y2[k], dz = q.z - z2[k];
            float d2 = dx * dx + dy * dy + dz * dz;
            bool upd = d2 < v[k];
            v[k] = upd ? d2 : v[k];
            imin[k] = upd ? r : imin[k];
        }
    }
#pragma unroll
    for (int k = 0; k < NSLOT; ++k) v[k] = sqrtf(v[k]);

    // ---- greedy matching on zero-reduced-cost edges ----
#pragma unroll
    for (int k = 0; k < NSLOT; ++k) {
        int j = 1 + k * 64 + lane;
        int r = imin[k];
        int old = atomicCAS(&rowm[r], 0, j);
        p_lds[j] = (old == 0) ? r : 0;
    }
    __syncthreads();

    // ---- successive shortest path for remaining (unmatched) rows ----
    for (int i = 1; i <= N; ++i) {
        if (rowm[i] != 0) continue;        // matched in init (uniform branch)

        float minv[NSLOT];   // absolute path distances
        int   way[NSLOT];
#pragma unroll
        for (int k = 0; k < NSLOT; ++k) { minv[k] = INFV; way[k] = 0; }
        unsigned used = 0u;
        float Dprev = 0.0f;

        if (lane == 0) p_lds[0] = i;
        __syncthreads();

        int j0 = 0;
        int guard = 0;
        for (;;) {
            int i0 = __builtin_amdgcn_readfirstlane(p_lds[j0]);
            if (i0 == 0) break;            // unmatched column found -> augment
            if (++guard > N + 2) break;    // safety

            if (j0 > 0) {                  // settle column j0
                int c = j0 - 1;
                int k0 = c >> 6, l0 = c & 63;
                if (lane == 0) dentry[j0] = Dprev;
                bool me = (lane == l0);
                if (me) used |= (1u << k0);
#pragma unroll
                for (int k = 0; k < NSLOT; ++k)
                    minv[k] = (me && k == k0) ? INFV : minv[k];
            }

            // expand from row i0 (pre-row-step potentials)
            float4 q = s1u[i0];            // {x,y,z,u[i0]} one ds_read_b128
            float base = Dprev - q.w;
#pragma unroll
            for (int k = 0; k < NSLOT; ++k) {
                float dx = q.x - x2[k], dy = q.y - y2[k], dz = q.z - z2[k];
                float d = sqrtf(dx * dx + dy * dy + dz * dz);
                float curabs = d + (base - v[k]);
                bool upd = (curabs < minv[k]) && !((used >> k) & 1u);
                minv[k] = upd ? curabs : minv[k];
                way[k]  = upd ? j0 : way[k];
            }

            // argmin over 1024 columns
            float bestv = minv[0];
            int   bestj = 1 + lane;
#pragma unroll
            for (int k = 1; k < NSLOT; ++k) {
                int j = 1 + k * 64 + lane;
                if (minv[k] < bestv) { bestv = minv[k]; bestj = j; }
            }
            float gmin = wave_min_f32(bestv);
            unsigned long long m = __ballot(bestv == gmin);
            int src = __ffsll((long long)m) - 1;
            j0 = __builtin_amdgcn_readlane(bestj, src);
            Dprev = gmin;
        }
        float DT = Dprev;
        __syncthreads();

        // deferred potential updates
        if (lane == 0) s1u[i].w += DT;     // u[i] += DT (column 0, dentry 0)
#pragma unroll
        for (int k = 0; k < NSLOT; ++k) {
            if ((used >> k) & 1u) {
                int j = 1 + k * 64 + lane;
                float dd = DT - dentry[j];
                v[k] -= dd;
                int r = p_lds[j];          // distinct rows across used cols
                s1u[r].w += dd;            // u[r] += dd, race-free
            }
        }
        __syncthreads();

        // augment along alternating path
        int aguard = 0;
        while (j0 != 0) {
            if (++aguard > N + 2) break;
            int c = j0 - 1;
            int k0 = c >> 6, l0 = c & 63;
            int wsel = way[0];
#pragma unroll
            for (int k = 1; k < NSLOT; ++k) wsel = (k == k0) ? way[k] : wsel;
            int j1 = __shfl(wsel, l0);
            int pj1 = p_lds[j1];
            if (lane == 0) { p_lds[j0] = pj1; rowm[pj1] = j0; }
            __syncthreads();
            j0 = j1;
        }
        __syncthreads();
    }

    // ---- total matched cost ----
    float sum = 0.0f;
#pragma unroll
    for (int k = 0; k < NSLOT; ++k) {
        int j = 1 + k * 64 + lane;
        int r = p_lds[j];
        float4 q = s1u[r];
        float dx = q.x - x2[k], dy = q.y - y2[k], dz = q.z - z2[k];
        sum += sqrtf(dx * dx + dy * dy + dz * dz);
    }
#pragma unroll
    for (int off = 32; off >= 1; off >>= 1) sum += __shfl_xor(sum, off);
    if (lane == 0) atomicAdd(out, sum * (1.0f / ((float)N * (float)BATCH)));
}

extern "C" void kernel_launch(void* const* d_in, const int* in_sizes, int n_in,
                              void* d_out, int out_size, void* d_ws, size_t ws_size,
                              hipStream_t stream) {
    const float* S1 = (const float*)d_in[0];
    const float* S2 = (const float*)d_in[1];
    float* out = (float*)d_out;
    emd_zero_kernel<<<1, 1, 0, stream>>>(out);
    emd_jv_kernel<<<BATCH, 64, 0, stream>>>(S1, S2, out);
}

// Round 3
// 23166.148 us; speedup vs baseline: 3.6489x; 2.4593x over previous
//
#include <hip/hip_runtime.h>
#include <math.h>

// EarthMoverDistance: exact Hungarian (JV successive shortest path) with
// column-reduction + greedy init. B=8, N=1024, 3-D Euclidean cost.
// One wave per batch. Round-3 changes:
//  - 32MB cost-matrix cache in d_ws (fp32, one 4MB matrix per batch/XCD-L2);
//    expand = 4 coalesced dwordx4 loads instead of 16x(3sub+3fma+sqrt).
//  - matched-row p[] carried in registers, packed (p<<11)|j through the
//    argmin reduction: no LDS reads on the selection critical path.
//  - batch-settle all columns tied at the current min (exact: reduced costs
//    >= 0); settled slots marked minv=NaN (self-excluding in compares).
//  - deferred dual updates via dentry[] (validated rounds 1-2, absmax 0.0).

#define N     1024
#define BATCH 8
#define NSLOT 16          // columns per lane: lane owns c = lane*16+k
#define INFV  1e9f

__global__ void emd_zero_kernel(float* out) { out[0] = 0.0f; }

// ---- cost cache: D[b][r][c] = dist(S1[b][r], S2[b][c]) ----
__global__ __launch_bounds__(256)
void emd_dist_kernel(const float* __restrict__ S1, const float* __restrict__ S2,
                     float* __restrict__ D) {
    int b = blockIdx.x >> 10;
    int r = blockIdx.x & (N - 1);
    const float* s1 = S1 + ((size_t)b * N + r) * 3;
    float x1 = s1[0], y1 = s1[1], z1 = s1[2];
    const float* s2 = S2 + (size_t)b * N * 3;
    float* drow = D + ((size_t)b * N + r) * (size_t)N;
    for (int c = threadIdx.x; c < N; c += 256) {
        float dx = x1 - s2[3 * c], dy = y1 - s2[3 * c + 1], dz = z1 - s2[3 * c + 2];
        drow[c] = sqrtf(dx * dx + dy * dy + dz * dz);
    }
}

// ---- column reduction: v[c] = min_r D[r][c], imin[c] = argmin (first) ----
__global__ __launch_bounds__(256)
void emd_colmin_kernel(const float* __restrict__ D, float* __restrict__ V,
                       int* __restrict__ I) {
    int b = blockIdx.x >> 2;
    int c = ((blockIdx.x & 3) << 8) + threadIdx.x;
    const float* Db = D + ((size_t)b << 20);
    float best = INFV; int bi = 1;
    for (int r = 0; r < N; ++r) {
        float d = Db[(size_t)r * N + c];
        if (d < best) { best = d; bi = r + 1; }
    }
    V[b * N + c] = best;
    I[b * N + c] = bi;
}

template<int CTRL>
__device__ __forceinline__ float dppmin(float x) {
    int xi = __float_as_int(x);
    int yi = __builtin_amdgcn_update_dpp(xi, xi, CTRL, 0xF, 0xF, false);
    return fminf(x, __int_as_float(yi));
}

__device__ __forceinline__ float wave_min_f32(float x) {
    x = dppmin<0x111>(x);   // row_shr:1
    x = dppmin<0x112>(x);   // row_shr:2
    x = dppmin<0x114>(x);   // row_shr:4
    x = dppmin<0x118>(x);   // row_shr:8
    x = dppmin<0x142>(x);   // row_bcast:15
    x = dppmin<0x143>(x);   // row_bcast:31 -> lane 63 has global min
    return __int_as_float(__builtin_amdgcn_readlane(__float_as_int(x), 63));
}

template<bool CACHED>
__global__ __launch_bounds__(64, 1)
void emd_jv_kernel(const float* __restrict__ S1,
                   const float* __restrict__ S2,
                   const float* __restrict__ Dc,    // cost cache (CACHED)
                   const float* __restrict__ Vin,   // column duals (CACHED)
                   const int*   __restrict__ Iin,   // argmin rows  (CACHED)
                   float* __restrict__ out) {
    __shared__ float4 s1u[N + 1];     // row coords (fallback path)
    __shared__ float  u_lds[N + 1];   // row potentials
    __shared__ float  dentry[N + 1];  // D value when column settled
    __shared__ int    rowm[N + 1];    // row -> matched col (0 = free)

    const int lane = threadIdx.x;
    const int b = blockIdx.x;
    const float* s1g = S1 + (size_t)b * N * 3;
    const float* s2g = S2 + (size_t)b * N * 3;
    const float* Db = CACHED ? (Dc + ((size_t)b << 20)) : (const float*)0;
    const float NANF = __int_as_float(0x7fc00000);

    for (int t = lane; t < N; t += 64) {
        if (!CACHED)
            s1u[t + 1] = make_float4(s1g[3 * t], s1g[3 * t + 1], s1g[3 * t + 2], 0.0f);
        u_lds[t + 1] = 0.0f;
        rowm[t + 1] = 0;
    }
    if (lane == 0) { u_lds[0] = 0.0f; rowm[0] = 0; }

    // ---- per-lane column state: col j = c+1, c = lane*16+k ----
    float v[NSLOT];       // column potentials
    int   pr[NSLOT];      // matched row (0 = free)
    int   jpk[NSLOT];     // packed (pr<<11)|j
    int   imin[NSLOT];
    float x2[NSLOT], y2[NSLOT], z2[NSLOT];   // fallback only

    if (CACHED) {
#pragma unroll
        for (int k = 0; k < NSLOT; ++k) {
            int c = lane * NSLOT + k;
            v[k] = Vin[b * N + c];
            imin[k] = Iin[b * N + c];
        }
    } else {
#pragma unroll
        for (int k = 0; k < NSLOT; ++k) {
            int pt = lane * NSLOT + k;
            x2[k] = s2g[3 * pt + 0];
            y2[k] = s2g[3 * pt + 1];
            z2[k] = s2g[3 * pt + 2];
            v[k] = INFV; imin[k] = 1;
        }
    }
    __syncthreads();

    if (!CACHED) {
        // in-wave column reduction (squared dists; sqrt at end — same argmin)
        for (int r = 1; r <= N; ++r) {
            float4 q = s1u[r];
#pragma unroll
            for (int k = 0; k < NSLOT; ++k) {
                float dx = q.x - x2[k], dy = q.y - y2[k], dz = q.z - z2[k];
                float d2 = dx * dx + dy * dy + dz * dz;
                bool upd = d2 < v[k];
                v[k] = upd ? d2 : v[k];
                imin[k] = upd ? r : imin[k];
            }
        }
#pragma unroll
        for (int k = 0; k < NSLOT; ++k) v[k] = sqrtf(v[k]);
    }

    // ---- greedy matching on tight edges ----
#pragma unroll
    for (int k = 0; k < NSLOT; ++k) {
        int j = lane * NSLOT + k + 1;
        int r = imin[k];
        int old = atomicCAS(&rowm[r], 0, j);
        pr[k] = (old == 0) ? r : 0;
        jpk[k] = (pr[k] << 11) | j;
    }
    __syncthreads();

    float minv[NSLOT];
    int   way[NSLOT];

    // ---- expand helper: relax all owned columns from row r at distance Dh ----
    auto expand = [&](int r, int jpred, float Dh) {
        if (CACHED) {
            const float4* dr4 = (const float4*)(Db + (size_t)(r - 1) * N);
            float4 qa = dr4[lane * 4 + 0];
            float4 qb = dr4[lane * 4 + 1];
            float4 qc = dr4[lane * 4 + 2];
            float4 qd = dr4[lane * 4 + 3];
            float base = Dh - u_lds[r];
            float dvv[NSLOT] = {qa.x, qa.y, qa.z, qa.w, qb.x, qb.y, qb.z, qb.w,
                                qc.x, qc.y, qc.z, qc.w, qd.x, qd.y, qd.z, qd.w};
#pragma unroll
            for (int k = 0; k < NSLOT; ++k) {
                float curabs = (dvv[k] - v[k]) + base;
                bool upd = curabs < minv[k];     // false for NaN (settled)
                minv[k] = upd ? curabs : minv[k];
                way[k] = upd ? jpred : way[k];
            }
        } else {
            float4 q = s1u[r];
            float base = Dh - u_lds[r];
#pragma unroll
            for (int k = 0; k < NSLOT; ++k) {
                float dx = q.x - x2[k], dy = q.y - y2[k], dz = q.z - z2[k];
                float d = sqrtf(dx * dx + dy * dy + dz * dz);
                float curabs = (d - v[k]) + base;
                bool upd = curabs < minv[k];
                minv[k] = upd ? curabs : minv[k];
                way[k] = upd ? jpred : way[k];
            }
        }
    };

    // ---- successive shortest paths for remaining free rows ----
    for (int i = 1; i <= N; ++i) {
        if (rowm[i] != 0) continue;

#pragma unroll
        for (int k = 0; k < NSLOT; ++k) { minv[k] = INFV; way[k] = 0; }
        unsigned used = 0u;
        float DT = 0.0f;
        int freecol = 0;

        expand(i, 0, 0.0f);

        int guard = 0;
        for (;;) {
            if (++guard > N + 4) break;
            // local argmin carrying packed (p, j)
            float bestv = INFV; int bestjp = 0;
#pragma unroll
            for (int k = 0; k < NSLOT; ++k) {
                bool t = minv[k] < bestv;        // NaN-safe skip of settled
                bestv = t ? minv[k] : bestv;
                bestjp = t ? jpk[k] : bestjp;
            }
            float gmin = wave_min_f32(bestv);
            if (!(gmin < INFV * 0.5f)) break;    // unreachable (shouldn't happen)
            unsigned long long tm = __ballot(bestv == gmin);
            DT = gmin;
            freecol = 0;
            // settle every column tied at gmin (one per owning lane per round)
            while (tm) {
                int l = __ffsll((long long)tm) - 1;
                tm &= tm - 1;
                int jp = __builtin_amdgcn_readlane(bestjp, l);
                int jj = jp & 0x7FF;
                int rr = jp >> 11;
                if (rr == 0) { freecol = jj; break; }   // free column reached
                {   // settle jj: mark NaN + used + dentry
                    int cc = jj - 1;
                    int lo = cc >> 4, kk = cc & 15;
                    if (lane == 0) dentry[jj] = gmin;
                    bool mine = (lane == lo);
#pragma unroll
                    for (int k = 0; k < NSLOT; ++k)
                        if (k == kk) {
                            if (mine) { minv[k] = NANF; used |= (1u << k); }
                        }
                }
                expand(rr, jj, gmin);
            }
            if (freecol) break;
        }
        if (freecol == 0) continue;   // defensive (guards tripped)

        // ---- deferred dual updates (pre-augment pr) ----
        if (lane == 0) u_lds[i] += DT;
#pragma unroll
        for (int k = 0; k < NSLOT; ++k) {
            if ((used >> k) & 1u) {
                int j = lane * NSLOT + k + 1;
                float dd = DT - dentry[j];
                v[k] -= dd;
                u_lds[pr[k]] += dd;      // distinct rows: race-free
            }
        }
        __syncthreads();

        // ---- augment along alternating path (register p via shuffles) ----
        int j0 = freecol;
        int aguard = 0;
        while (j0 != 0) {
            if (++aguard > N + 4) break;
            int cc = j0 - 1;
            int lo = cc >> 4, kk = cc & 15;
            int wloc = way[0];
#pragma unroll
            for (int k = 1; k < NSLOT; ++k) if (k == kk) wloc = way[k];
            int j1 = __builtin_amdgcn_readlane(wloc, lo);
            int np;
            if (j1 == 0) np = i;
            else {
                int c1 = j1 - 1;
                int lo1 = c1 >> 4, kk1 = c1 & 15;
                int ploc = pr[0];
#pragma unroll
                for (int k = 1; k < NSLOT; ++k) if (k == kk1) ploc = pr[k];
                np = __builtin_amdgcn_readlane(ploc, lo1);
            }
            bool mine = (lane == lo);
#pragma unroll
            for (int k = 0; k < NSLOT; ++k)
                if (k == kk) {
                    if (mine) { pr[k] = np; jpk[k] = (np << 11) | j0; }
                }
            if (lane == 0) rowm[np] = j0;
            j0 = j1;
        }
        __syncthreads();
    }

    // ---- total matched cost ----
    float sum = 0.0f;
#pragma unroll
    for (int k = 0; k < NSLOT; ++k) {
        int c = lane * NSLOT + k;
        int r = pr[k] > 0 ? pr[k] : 1;
        if (CACHED) {
            sum += Db[(size_t)(r - 1) * N + c];
        } else {
            float4 q = s1u[r];
            float dx = q.x - x2[k], dy = q.y - y2[k], dz = q.z - z2[k];
            sum += sqrtf(dx * dx + dy * dy + dz * dz);
        }
    }
#pragma unroll
    for (int off = 32; off >= 1; off >>= 1) sum += __shfl_xor(sum, off);
    if (lane == 0) atomicAdd(out, sum * (1.0f / ((float)N * (float)BATCH)));
}

extern "C" void kernel_launch(void* const* d_in, const int* in_sizes, int n_in,
                              void* d_out, int out_size, void* d_ws, size_t ws_size,
                              hipStream_t stream) {
    const float* S1 = (const float*)d_in[0];
    const float* S2 = (const float*)d_in[1];
    float* out = (float*)d_out;

    size_t needD = (size_t)BATCH * N * N * sizeof(float);
    size_t needT = needD + (size_t)BATCH * N * (sizeof(float) + sizeof(int));

    emd_zero_kernel<<<1, 1, 0, stream>>>(out);

    if (ws_size >= needT) {
        float* D = (float*)d_ws;
        float* V = (float*)((char*)d_ws + needD);
        int*   I = (int*)(V + BATCH * N);
        emd_dist_kernel<<<BATCH * N, 256, 0, stream>>>(S1, S2, D);
        emd_colmin_kernel<<<BATCH * 4, 256, 0, stream>>>(D, V, I);
        emd_jv_kernel<true><<<BATCH, 64, 0, stream>>>(S1, S2, D, V, I, out);
    } else {
        emd_jv_kernel<false><<<BATCH, 64, 0, stream>>>(S1, S2, nullptr, nullptr, nullptr, out);
    }
}